// Round 3
// baseline (173.541 us; speedup 1.0000x reference)
//
#include <hip/hip_runtime.h>
#include <hip/hip_bf16.h>
#include <hip/hip_fp16.h>
#include <stdint.h>

typedef _Float16 half8 __attribute__((ext_vector_type(8)));
typedef _Float16 half4_t __attribute__((ext_vector_type(4)));
typedef float f32x4 __attribute__((ext_vector_type(4)));

// async global->LDS, 16B per lane. LDS dst must be wave-uniform base + lane*16.
__device__ __forceinline__ void lds_load16(const _Float16* g, _Float16* l) {
    __builtin_amdgcn_global_load_lds(
        (const __attribute__((address_space(1))) void*)g,
        (__attribute__((address_space(3))) void*)l, 16, 0, 0);
}

// ---------------------------------------------------------------------------
// fp32 -> fp16 conversions: nodes (8192x512), Wcat = [Wq;Wk;Wv], Wo
// ---------------------------------------------------------------------------
__global__ __launch_bounds__(256) void prep_convert(
    const float* __restrict__ nodes, const float* __restrict__ wq,
    const float* __restrict__ wk, const float* __restrict__ wv,
    const float* __restrict__ wo,
    _Float16* __restrict__ x16, _Float16* __restrict__ wcat,
    _Float16* __restrict__ wo16)
{
    const int t = blockIdx.x * 256 + threadIdx.x;   // 0 .. 1048575
    {
        const float4 v = ((const float4*)nodes)[t];
        half4_t o;
        o[0] = (_Float16)v.x; o[1] = (_Float16)v.y;
        o[2] = (_Float16)v.z; o[3] = (_Float16)v.w;
        *(half4_t*)(x16 + (size_t)t * 4) = o;
    }
    if (t < 65536) {
        float4 v; half4_t o;
        v = ((const float4*)wq)[t];
        o[0]=(_Float16)v.x; o[1]=(_Float16)v.y; o[2]=(_Float16)v.z; o[3]=(_Float16)v.w;
        *(half4_t*)(wcat + (size_t)t * 4) = o;
        v = ((const float4*)wk)[t];
        o[0]=(_Float16)v.x; o[1]=(_Float16)v.y; o[2]=(_Float16)v.z; o[3]=(_Float16)v.w;
        *(half4_t*)(wcat + 262144 + (size_t)t * 4) = o;
        v = ((const float4*)wv)[t];
        o[0]=(_Float16)v.x; o[1]=(_Float16)v.y; o[2]=(_Float16)v.z; o[3]=(_Float16)v.w;
        *(half4_t*)(wcat + 524288 + (size_t)t * 4) = o;
        v = ((const float4*)wo)[t];
        o[0]=(_Float16)v.x; o[1]=(_Float16)v.y; o[2]=(_Float16)v.z; o[3]=(_Float16)v.w;
        *(half4_t*)(wo16 + (size_t)t * 4) = o;
    }
}

// ---------------------------------------------------------------------------
// QKV projection: X[8192,512] @ Wcat[1536,512]^T -> scatter q/k/v [bh][i][d]
// q is pre-scaled by 1/sqrt(64) here (free in the epilogue).
// ---------------------------------------------------------------------------
__global__ __launch_bounds__(256) void gemm_qkv(
    const _Float16* __restrict__ X, const _Float16* __restrict__ Wcat,
    const float* __restrict__ bq, const float* __restrict__ bk,
    const float* __restrict__ bv,
    _Float16* __restrict__ q16, _Float16* __restrict__ k16,
    _Float16* __restrict__ v16)
{
    __shared__ _Float16 As[128 * 32];
    __shared__ _Float16 Bs[128 * 32];
    const int t = threadIdx.x;
    const int bm = blockIdx.x, bn = blockIdx.y;
    const int wave = t >> 6, lane = t & 63;
    const int wm = (wave >> 1) * 64, wn = (wave & 1) * 64;
    const int quad = lane >> 4, l16 = lane & 15;

    f32x4 acc[4][4];
#pragma unroll
    for (int a = 0; a < 4; a++)
#pragma unroll
        for (int b2 = 0; b2 < 4; b2++) acc[a][b2] = (f32x4){0.f, 0.f, 0.f, 0.f};

    const _Float16* Ab = X + (size_t)bm * 128 * 512;
    const _Float16* Bb = Wcat + (size_t)bn * 128 * 512;
    const int srow = t >> 2, scol = (t & 3) * 8;

    for (int k0 = 0; k0 < 512; k0 += 32) {
        __syncthreads();
        lds_load16(Ab + (size_t)srow * 512 + k0 + scol, As + t * 8);
        lds_load16(Ab + (size_t)(srow + 64) * 512 + k0 + scol, As + 2048 + t * 8);
        lds_load16(Bb + (size_t)srow * 512 + k0 + scol, Bs + t * 8);
        lds_load16(Bb + (size_t)(srow + 64) * 512 + k0 + scol, Bs + 2048 + t * 8);
        __syncthreads();
        half8 af[4], bf[4];
#pragma unroll
        for (int mi = 0; mi < 4; mi++)
            af[mi] = *(const half8*)&As[(wm + mi * 16 + l16) * 32 + quad * 8];
#pragma unroll
        for (int ni = 0; ni < 4; ni++)
            bf[ni] = *(const half8*)&Bs[(wn + ni * 16 + l16) * 32 + quad * 8];
#pragma unroll
        for (int mi = 0; mi < 4; mi++)
#pragma unroll
            for (int ni = 0; ni < 4; ni++)
                acc[mi][ni] = __builtin_amdgcn_mfma_f32_16x16x32_f16(
                    af[mi], bf[ni], acc[mi][ni], 0, 0, 0);
    }

    const int sel = bn >> 2;
    const float* bias = sel == 0 ? bq : (sel == 1 ? bk : bv);
    _Float16* outp = sel == 0 ? q16 : (sel == 1 ? k16 : v16);
    const float scale = sel == 0 ? 0.125f : 1.0f;   // fold 1/sqrt(D) into q
    const int colbase = (bn & 3) * 128 + wn + l16;
#pragma unroll
    for (int mi = 0; mi < 4; mi++) {
#pragma unroll
        for (int r = 0; r < 4; r++) {
            const int m = bm * 128 + wm + mi * 16 + quad * 4 + r;
            const int ii = m >> 3, bb = m & 7;
#pragma unroll
            for (int ni = 0; ni < 4; ni++) {
                const int f = colbase + ni * 16;
                const int hh = f >> 6, dd = f & 63;
                const float val = (acc[mi][ni][r] + bias[f]) * scale;
                outp[(size_t)((bb * 8 + hh) * 1024 + ii) * 64 + dd] = (_Float16)val;
            }
        }
    }
}

// ---------------------------------------------------------------------------
// Flash-style MFMA attention. Block = (b,h) x 64 q-rows; 4 waves x 16 rows.
// grid (16,64) = 1024 blocks -> 4 blocks/CU resident (LDS 35,072 B).
// Per 64-j tile: stage K and V^T (transposed in LDS during staging),
// S = qK^T via mfma 16x16x32_f16, add edges*rel_bias, p = exp(s - 8ln2)
// (shift cancels in O = sum pV / sum p), P->LDS f16 -> A-frag, PV MFMA.
// ---------------------------------------------------------------------------
__global__ __launch_bounds__(256, 4) void attn_fused(
    const _Float16* __restrict__ q16, const _Float16* __restrict__ k16,
    const _Float16* __restrict__ v16, const float* __restrict__ edges,
    const float* __restrict__ rel_bias, _Float16* __restrict__ attn16)
{
    __shared__ _Float16 Qs[64][68];     //  8,704 B
    __shared__ _Float16 Ks[64][68];     //  8,704 B
    __shared__ _Float16 Vts[64][70];    //  8,960 B (stride 70: transpose writes <=2-way)
    __shared__ _Float16 Ps[64][68];     //  8,704 B

    const int t = threadIdx.x;
    const int bh = blockIdx.y;
    const int b = bh >> 3, h = bh & 7;
    const int i0 = blockIdx.x * 64;
    const int wave = t >> 6, lane = t & 63;
    const int quad = lane >> 4, l16 = lane & 15;
    const int qb = wave * 16;
    const float rb = rel_bias[h];
    const float SHIFT = 5.545177444f;   // 8*ln2

    const _Float16* Qb = q16 + (size_t)bh * 1024 * 64;
    const _Float16* Kb = k16 + (size_t)bh * 1024 * 64;
    const _Float16* Vb = v16 + (size_t)bh * 1024 * 64;

    const int srow = t >> 2, scol = (t & 3) * 16;

    {   // Q tile 64x64 (already scaled in gemm_qkv)
        *(half8*)&Qs[srow][scol]     = *(const half8*)(Qb + (size_t)(i0 + srow) * 64 + scol);
        *(half8*)&Qs[srow][scol + 8] = *(const half8*)(Qb + (size_t)(i0 + srow) * 64 + scol + 8);
    }

    f32x4 acc_o[4];
    float lsum[4];
#pragma unroll
    for (int nd = 0; nd < 4; nd++) acc_o[nd] = (f32x4){0.f, 0.f, 0.f, 0.f};
#pragma unroll
    for (int r = 0; r < 4; r++) lsum[r] = 0.f;

    for (int jt = 0; jt < 1024; jt += 64) {
        __syncthreads();   // previous iteration's LDS reads done
        {   // stage K[64x64] and V^T (transpose during staging)
            half8 k0 = *(const half8*)(Kb + (size_t)(jt + srow) * 64 + scol);
            half8 k1 = *(const half8*)(Kb + (size_t)(jt + srow) * 64 + scol + 8);
            half8 v0 = *(const half8*)(Vb + (size_t)(jt + srow) * 64 + scol);
            half8 v1 = *(const half8*)(Vb + (size_t)(jt + srow) * 64 + scol + 8);
            *(half8*)&Ks[srow][scol]     = k0;
            *(half8*)&Ks[srow][scol + 8] = k1;
#pragma unroll
            for (int e = 0; e < 8; e++) {
                Vts[scol + e][srow]     = v0[e];
                Vts[scol + 8 + e][srow] = v1[e];
            }
        }
        // prefetch edge bias (independent of LDS; overlaps barrier wait)
        float eb[4][4];
#pragma unroll
        for (int nt = 0; nt < 4; nt++) {
            const size_t rowb = (size_t)(i0 + qb + quad * 4) * 1024;
#pragma unroll
            for (int r = 0; r < 4; r++)
                eb[nt][r] = edges[rowb + (size_t)r * 1024 + jt + nt * 16 + l16];
        }
        __syncthreads();

        // ---- S = Q K^T ----
        f32x4 s[4];
#pragma unroll
        for (int nt = 0; nt < 4; nt++) s[nt] = (f32x4){0.f, 0.f, 0.f, 0.f};
#pragma unroll
        for (int kk = 0; kk < 2; kk++) {
            half8 aq = *(const half8*)&Qs[qb + l16][kk * 32 + quad * 8];
#pragma unroll
            for (int nt = 0; nt < 4; nt++) {
                half8 bk8 = *(const half8*)&Ks[nt * 16 + l16][kk * 32 + quad * 8];
                s[nt] = __builtin_amdgcn_mfma_f32_16x16x32_f16(aq, bk8, s[nt], 0, 0, 0);
            }
        }

        // ---- bias + exp + partial rowsum + P->LDS f16 (wave-private rows) ----
#pragma unroll
        for (int nt = 0; nt < 4; nt++)
#pragma unroll
            for (int r = 0; r < 4; r++) {
                const float sv = fmaf(eb[nt][r], rb, s[nt][r]);
                const float p = __expf(sv - SHIFT);
                lsum[r] += p;
                Ps[qb + quad * 4 + r][nt * 16 + l16] = (_Float16)p;
            }

        // ---- P A-frags + PV MFMA ----
#pragma unroll
        for (int kk = 0; kk < 2; kk++) {
            half8 pa = *(const half8*)&Ps[qb + l16][kk * 32 + quad * 8];
#pragma unroll
            for (int nd = 0; nd < 4; nd++) {
                half8 vb8 = *(const half8*)&Vts[nd * 16 + l16][kk * 32 + quad * 8];
                acc_o[nd] = __builtin_amdgcn_mfma_f32_16x16x32_f16(pa, vb8, acc_o[nd], 0, 0, 0);
            }
        }
    }

    // ---- finalize: reduce lsum over the 16 col-lanes, divide, store ----
#pragma unroll
    for (int r = 0; r < 4; r++) {
        float l = lsum[r];
#pragma unroll
        for (int d = 1; d < 16; d <<= 1) l += __shfl_xor(l, d);
        lsum[r] = 1.0f / l;
    }
#pragma unroll
    for (int r = 0; r < 4; r++) {
        const int i = i0 + qb + quad * 4 + r;
        _Float16* orow = attn16 + ((size_t)i * 8 + b) * 512 + h * 64;
#pragma unroll
        for (int nd = 0; nd < 4; nd++)
            orow[nd * 16 + l16] = (_Float16)(acc_o[nd][r] * lsum[r]);
    }
}

// ---------------------------------------------------------------------------
// Output projection: attn16[8192,512] @ Wo[512,512]^T + bo -> d_out fp32
// ---------------------------------------------------------------------------
__global__ __launch_bounds__(256) void gemm_out(
    const _Float16* __restrict__ A, const _Float16* __restrict__ W,
    const float* __restrict__ bo, float* __restrict__ dout)
{
    __shared__ _Float16 As[128 * 32];
    __shared__ _Float16 Bs[128 * 32];
    const int t = threadIdx.x;
    const int bm = blockIdx.x, bn = blockIdx.y;
    const int wave = t >> 6, lane = t & 63;
    const int wm = (wave >> 1) * 64, wn = (wave & 1) * 64;
    const int quad = lane >> 4, l16 = lane & 15;

    f32x4 acc[4][4];
#pragma unroll
    for (int a = 0; a < 4; a++)
#pragma unroll
        for (int b2 = 0; b2 < 4; b2++) acc[a][b2] = (f32x4){0.f, 0.f, 0.f, 0.f};

    const _Float16* Ab = A + (size_t)bm * 128 * 512;
    const _Float16* Bb = W + (size_t)bn * 128 * 512;
    const int srow = t >> 2, scol = (t & 3) * 8;

    for (int k0 = 0; k0 < 512; k0 += 32) {
        __syncthreads();
        lds_load16(Ab + (size_t)srow * 512 + k0 + scol, As + t * 8);
        lds_load16(Ab + (size_t)(srow + 64) * 512 + k0 + scol, As + 2048 + t * 8);
        lds_load16(Bb + (size_t)srow * 512 + k0 + scol, Bs + t * 8);
        lds_load16(Bb + (size_t)(srow + 64) * 512 + k0 + scol, Bs + 2048 + t * 8);
        __syncthreads();
        half8 af[4], bf[4];
#pragma unroll
        for (int mi = 0; mi < 4; mi++)
            af[mi] = *(const half8*)&As[(wm + mi * 16 + l16) * 32 + quad * 8];
#pragma unroll
        for (int ni = 0; ni < 4; ni++)
            bf[ni] = *(const half8*)&Bs[(wn + ni * 16 + l16) * 32 + quad * 8];
#pragma unroll
        for (int mi = 0; mi < 4; mi++)
#pragma unroll
            for (int ni = 0; ni < 4; ni++)
                acc[mi][ni] = __builtin_amdgcn_mfma_f32_16x16x32_f16(
                    af[mi], bf[ni], acc[mi][ni], 0, 0, 0);
    }
#pragma unroll
    for (int mi = 0; mi < 4; mi++) {
#pragma unroll
        for (int r = 0; r < 4; r++) {
            const int m = bm * 128 + wm + mi * 16 + quad * 4 + r;
#pragma unroll
            for (int ni = 0; ni < 4; ni++) {
                const int n = bn * 128 + wn + ni * 16 + l16;
                dout[(size_t)m * 512 + n] = acc[mi][ni][r] + bo[n];
            }
        }
    }
}

// ---------------------------------------------------------------------------
extern "C" void kernel_launch(void* const* d_in, const int* in_sizes, int n_in,
                              void* d_out, int out_size, void* d_ws, size_t ws_size,
                              hipStream_t stream)
{
    (void)in_sizes; (void)n_in; (void)out_size; (void)ws_size;
    const float* nodes    = (const float*)d_in[0];
    const float* edges    = (const float*)d_in[1];
    const float* Wq       = (const float*)d_in[2];
    const float* bq       = (const float*)d_in[3];
    const float* Wk       = (const float*)d_in[4];
    const float* bk       = (const float*)d_in[5];
    const float* Wv       = (const float*)d_in[6];
    const float* bv       = (const float*)d_in[7];
    const float* rel_bias = (const float*)d_in[8];
    const float* Wo       = (const float*)d_in[9];
    const float* bo       = (const float*)d_in[10];
    float* out = (float*)d_out;

    char* ws = (char*)d_ws;
    _Float16* x16    = (_Float16*)(ws);              //  8,388,608 B
    _Float16* wcat   = (_Float16*)(ws +  8388608);   //  1,572,864 B
    _Float16* wo16   = (_Float16*)(ws +  9961472);   //    524,288 B
    _Float16* q16    = (_Float16*)(ws + 10485760);   //  8,388,608 B
    _Float16* k16    = (_Float16*)(ws + 18874368);   //  8,388,608 B
    _Float16* v16    = (_Float16*)(ws + 27262976);   //  8,388,608 B
    _Float16* attn16 = (_Float16*)(ws + 35651584);   //  8,388,608 B

    hipLaunchKernelGGL(prep_convert, dim3(4096), dim3(256), 0, stream,
                       nodes, Wq, Wk, Wv, Wo, x16, wcat, wo16);
    hipLaunchKernelGGL(gemm_qkv, dim3(64, 12), dim3(256), 0, stream,
                       x16, wcat, bq, bk, bv, q16, k16, v16);
    hipLaunchKernelGGL(attn_fused, dim3(16, 64), dim3(256), 0, stream,
                       q16, k16, v16, edges, rel_bias, attn16);
    hipLaunchKernelGGL(gemm_out, dim3(64, 4), dim3(256), 0, stream,
                       attn16, wo16, bo, out);
}

// Round 4
// 166.221 us; speedup vs baseline: 1.0440x; 1.0440x over previous
//
#include <hip/hip_runtime.h>
#include <hip/hip_bf16.h>
#include <hip/hip_fp16.h>
#include <stdint.h>

typedef _Float16 half8 __attribute__((ext_vector_type(8)));
typedef _Float16 half4_t __attribute__((ext_vector_type(4)));
typedef float f32x4 __attribute__((ext_vector_type(4)));

// async global->LDS, 16B per lane. LDS dst must be wave-uniform base + lane*16.
__device__ __forceinline__ void lds_load16(const _Float16* g, _Float16* l) {
    __builtin_amdgcn_global_load_lds(
        (const __attribute__((address_space(1))) void*)g,
        (__attribute__((address_space(3))) void*)l, 16, 0, 0);
}

// ---------------------------------------------------------------------------
// fp32 -> fp16 conversions: nodes (8192x512), Wcat = [Wq;Wk;Wv], Wo
// ---------------------------------------------------------------------------
__global__ __launch_bounds__(256) void prep_convert(
    const float* __restrict__ nodes, const float* __restrict__ wq,
    const float* __restrict__ wk, const float* __restrict__ wv,
    const float* __restrict__ wo,
    _Float16* __restrict__ x16, _Float16* __restrict__ wcat,
    _Float16* __restrict__ wo16)
{
    const int t = blockIdx.x * 256 + threadIdx.x;   // 0 .. 1048575
    {
        const float4 v = ((const float4*)nodes)[t];
        half4_t o;
        o[0] = (_Float16)v.x; o[1] = (_Float16)v.y;
        o[2] = (_Float16)v.z; o[3] = (_Float16)v.w;
        *(half4_t*)(x16 + (size_t)t * 4) = o;
    }
    if (t < 65536) {
        float4 v; half4_t o;
        v = ((const float4*)wq)[t];
        o[0]=(_Float16)v.x; o[1]=(_Float16)v.y; o[2]=(_Float16)v.z; o[3]=(_Float16)v.w;
        *(half4_t*)(wcat + (size_t)t * 4) = o;
        v = ((const float4*)wk)[t];
        o[0]=(_Float16)v.x; o[1]=(_Float16)v.y; o[2]=(_Float16)v.z; o[3]=(_Float16)v.w;
        *(half4_t*)(wcat + 262144 + (size_t)t * 4) = o;
        v = ((const float4*)wv)[t];
        o[0]=(_Float16)v.x; o[1]=(_Float16)v.y; o[2]=(_Float16)v.z; o[3]=(_Float16)v.w;
        *(half4_t*)(wcat + 524288 + (size_t)t * 4) = o;
        v = ((const float4*)wo)[t];
        o[0]=(_Float16)v.x; o[1]=(_Float16)v.y; o[2]=(_Float16)v.z; o[3]=(_Float16)v.w;
        *(half4_t*)(wo16 + (size_t)t * 4) = o;
    }
}

// ---------------------------------------------------------------------------
// QKV projection: X[8192,512] @ Wcat[1536,512]^T -> scatter q/k/v [bh][i][d]
// q is pre-scaled by 1/sqrt(64) here (free in the epilogue).
// ---------------------------------------------------------------------------
__global__ __launch_bounds__(256, 3) void gemm_qkv(
    const _Float16* __restrict__ X, const _Float16* __restrict__ Wcat,
    const float* __restrict__ bq, const float* __restrict__ bk,
    const float* __restrict__ bv,
    _Float16* __restrict__ q16, _Float16* __restrict__ k16,
    _Float16* __restrict__ v16)
{
    __shared__ _Float16 As[128 * 32];
    __shared__ _Float16 Bs[128 * 32];
    const int t = threadIdx.x;
    const int bm = blockIdx.x, bn = blockIdx.y;
    const int wave = t >> 6, lane = t & 63;
    const int wm = (wave >> 1) * 64, wn = (wave & 1) * 64;
    const int quad = lane >> 4, l16 = lane & 15;

    f32x4 acc[4][4];
#pragma unroll
    for (int a = 0; a < 4; a++)
#pragma unroll
        for (int b2 = 0; b2 < 4; b2++) acc[a][b2] = (f32x4){0.f, 0.f, 0.f, 0.f};

    const _Float16* Ab = X + (size_t)bm * 128 * 512;
    const _Float16* Bb = Wcat + (size_t)bn * 128 * 512;
    const int srow = t >> 2, scol = (t & 3) * 8;

    for (int k0 = 0; k0 < 512; k0 += 32) {
        __syncthreads();
        lds_load16(Ab + (size_t)srow * 512 + k0 + scol, As + t * 8);
        lds_load16(Ab + (size_t)(srow + 64) * 512 + k0 + scol, As + 2048 + t * 8);
        lds_load16(Bb + (size_t)srow * 512 + k0 + scol, Bs + t * 8);
        lds_load16(Bb + (size_t)(srow + 64) * 512 + k0 + scol, Bs + 2048 + t * 8);
        __syncthreads();
        half8 af[4], bf[4];
#pragma unroll
        for (int mi = 0; mi < 4; mi++)
            af[mi] = *(const half8*)&As[(wm + mi * 16 + l16) * 32 + quad * 8];
#pragma unroll
        for (int ni = 0; ni < 4; ni++)
            bf[ni] = *(const half8*)&Bs[(wn + ni * 16 + l16) * 32 + quad * 8];
#pragma unroll
        for (int mi = 0; mi < 4; mi++)
#pragma unroll
            for (int ni = 0; ni < 4; ni++)
                acc[mi][ni] = __builtin_amdgcn_mfma_f32_16x16x32_f16(
                    af[mi], bf[ni], acc[mi][ni], 0, 0, 0);
    }

    const int sel = bn >> 2;
    const float* bias = sel == 0 ? bq : (sel == 1 ? bk : bv);
    _Float16* outp = sel == 0 ? q16 : (sel == 1 ? k16 : v16);
    const float scale = sel == 0 ? 0.125f : 1.0f;   // fold 1/sqrt(D) into q
    const int colbase = (bn & 3) * 128 + wn + l16;
#pragma unroll
    for (int mi = 0; mi < 4; mi++) {
#pragma unroll
        for (int r = 0; r < 4; r++) {
            const int m = bm * 128 + wm + mi * 16 + quad * 4 + r;
            const int ii = m >> 3, bb = m & 7;
#pragma unroll
            for (int ni = 0; ni < 4; ni++) {
                const int f = colbase + ni * 16;
                const int hh = f >> 6, dd = f & 63;
                const float val = (acc[mi][ni][r] + bias[f]) * scale;
                outp[(size_t)((bb * 8 + hh) * 1024 + ii) * 64 + dd] = (_Float16)val;
            }
        }
    }
}

// ---------------------------------------------------------------------------
// Flash-style MFMA attention. Block = (b,h) x 128 q-rows; 4 waves x 32 rows.
// grid (8,64) = 512 blocks; LDS 52,608 B -> 3 blocks/CU (12 waves/CU).
// Per 64-j tile: stage K + V^T (transpose during staging, stride 70),
// S = qK^T (q pre-scaled), add edges*rel_bias, p = exp(s - 8ln2) (shift
// cancels in O = sum pV / sum p), f16 P->LDS -> A-frag, PV MFMA.
// ---------------------------------------------------------------------------
__global__ __launch_bounds__(256, 3) void attn_fused(
    const _Float16* __restrict__ q16, const _Float16* __restrict__ k16,
    const _Float16* __restrict__ v16, const float* __restrict__ edges,
    const float* __restrict__ rel_bias, _Float16* __restrict__ attn16)
{
    __shared__ _Float16 Qs[128][68];    // 17,408 B
    __shared__ _Float16 Ks[64][68];     //  8,704 B
    __shared__ _Float16 Vts[64][70];    //  8,960 B (V^T; write conflicts <=4-way)
    __shared__ _Float16 Ps[128][68];    // 17,408 B (store pattern conflict-free)

    const int t = threadIdx.x;
    const int bh = blockIdx.y;
    const int b = bh >> 3, h = bh & 7;
    const int i0 = blockIdx.x * 128;
    const int wave = t >> 6, lane = t & 63;
    const int quad = lane >> 4, l16 = lane & 15;
    const int qb = wave * 32;
    const float rb = rel_bias[h];
    const float SHIFT = 5.545177444f;   // 8*ln2

    const _Float16* Qb = q16 + (size_t)bh * 1024 * 64;
    const _Float16* Kb = k16 + (size_t)bh * 1024 * 64;
    const _Float16* Vb = v16 + (size_t)bh * 1024 * 64;

    const int srow = t >> 2, scol = (t & 3) * 16;

    {   // Q tile 128x64 (already scaled by 1/8 in gemm_qkv)
#pragma unroll
        for (int rr = 0; rr < 128; rr += 64) {
            *(half8*)&Qs[rr + srow][scol] =
                *(const half8*)(Qb + (size_t)(i0 + rr + srow) * 64 + scol);
            *(half8*)&Qs[rr + srow][scol + 8] =
                *(const half8*)(Qb + (size_t)(i0 + rr + srow) * 64 + scol + 8);
        }
    }

    f32x4 acc_o[2][4];
    float lsum[2][4];
#pragma unroll
    for (int mt = 0; mt < 2; mt++) {
#pragma unroll
        for (int nd = 0; nd < 4; nd++) acc_o[mt][nd] = (f32x4){0.f, 0.f, 0.f, 0.f};
#pragma unroll
        for (int r = 0; r < 4; r++) lsum[mt][r] = 0.f;
    }

    for (int jt = 0; jt < 1024; jt += 64) {
        __syncthreads();   // previous iteration's LDS reads done
        {   // stage K[64x64] and V^T (transpose during staging)
            half8 k0 = *(const half8*)(Kb + (size_t)(jt + srow) * 64 + scol);
            half8 k1 = *(const half8*)(Kb + (size_t)(jt + srow) * 64 + scol + 8);
            half8 v0 = *(const half8*)(Vb + (size_t)(jt + srow) * 64 + scol);
            half8 v1 = *(const half8*)(Vb + (size_t)(jt + srow) * 64 + scol + 8);
            *(half8*)&Ks[srow][scol]     = k0;
            *(half8*)&Ks[srow][scol + 8] = k1;
#pragma unroll
            for (int e = 0; e < 8; e++) {
                Vts[scol + e][srow]     = v0[e];
                Vts[scol + 8 + e][srow] = v1[e];
            }
        }
        // prefetch edge bias (independent of LDS; overlaps barrier wait)
        float eb[2][4][4];
#pragma unroll
        for (int mt = 0; mt < 2; mt++) {
            const size_t rowb = (size_t)(i0 + qb + mt * 16 + quad * 4) * 1024;
#pragma unroll
            for (int nt = 0; nt < 4; nt++)
#pragma unroll
                for (int r = 0; r < 4; r++)
                    eb[mt][nt][r] = edges[rowb + (size_t)r * 1024 + jt + nt * 16 + l16];
        }
        __syncthreads();

        // ---- S = Q K^T ----
        f32x4 s[2][4];
#pragma unroll
        for (int mt = 0; mt < 2; mt++)
#pragma unroll
            for (int nt = 0; nt < 4; nt++) s[mt][nt] = (f32x4){0.f, 0.f, 0.f, 0.f};
#pragma unroll
        for (int kk = 0; kk < 2; kk++) {
            half8 aq[2], bk8[4];
#pragma unroll
            for (int mt = 0; mt < 2; mt++)
                aq[mt] = *(const half8*)&Qs[qb + mt * 16 + l16][kk * 32 + quad * 8];
#pragma unroll
            for (int nt = 0; nt < 4; nt++)
                bk8[nt] = *(const half8*)&Ks[nt * 16 + l16][kk * 32 + quad * 8];
#pragma unroll
            for (int mt = 0; mt < 2; mt++)
#pragma unroll
                for (int nt = 0; nt < 4; nt++)
                    s[mt][nt] = __builtin_amdgcn_mfma_f32_16x16x32_f16(
                        aq[mt], bk8[nt], s[mt][nt], 0, 0, 0);
        }

        // ---- bias + exp + partial rowsum + f16 P->LDS (wave-private rows) ----
#pragma unroll
        for (int mt = 0; mt < 2; mt++)
#pragma unroll
            for (int nt = 0; nt < 4; nt++)
#pragma unroll
                for (int r = 0; r < 4; r++) {
                    const float sv = fmaf(eb[mt][nt][r], rb, s[mt][nt][r]);
                    const float p = __expf(sv - SHIFT);
                    lsum[mt][r] += p;
                    Ps[qb + mt * 16 + quad * 4 + r][nt * 16 + l16] = (_Float16)p;
                }

        // ---- P A-frags (direct f16 read) + PV MFMA ----
#pragma unroll
        for (int kk = 0; kk < 2; kk++) {
            half8 pa[2];
#pragma unroll
            for (int mt = 0; mt < 2; mt++)
                pa[mt] = *(const half8*)&Ps[qb + mt * 16 + l16][kk * 32 + quad * 8];
#pragma unroll
            for (int nd = 0; nd < 4; nd++) {
                half8 vb8 = *(const half8*)&Vts[nd * 16 + l16][kk * 32 + quad * 8];
#pragma unroll
                for (int mt = 0; mt < 2; mt++)
                    acc_o[mt][nd] = __builtin_amdgcn_mfma_f32_16x16x32_f16(
                        pa[mt], vb8, acc_o[mt][nd], 0, 0, 0);
            }
        }
    }

    // ---- finalize: reduce lsum over the 16 col-lanes, divide, store ----
#pragma unroll
    for (int mt = 0; mt < 2; mt++)
#pragma unroll
        for (int r = 0; r < 4; r++) {
            float l = lsum[mt][r];
#pragma unroll
            for (int d = 1; d < 16; d <<= 1) l += __shfl_xor(l, d);
            lsum[mt][r] = 1.0f / l;
        }
#pragma unroll
    for (int mt = 0; mt < 2; mt++)
#pragma unroll
        for (int r = 0; r < 4; r++) {
            const int i = i0 + qb + mt * 16 + quad * 4 + r;
            _Float16* orow = attn16 + ((size_t)i * 8 + b) * 512 + h * 64;
#pragma unroll
            for (int nd = 0; nd < 4; nd++)
                orow[nd * 16 + l16] = (_Float16)(acc_o[mt][nd][r] * lsum[mt][r]);
        }
}

// ---------------------------------------------------------------------------
// Output projection: attn16[8192,512] @ Wo[512,512]^T + bo -> d_out fp32
// 64x128 tiles -> grid (128,4) = 512 blocks = 2 blocks/CU (was 1/CU at 128^2).
// 4 waves: each 32x64 (2x4 MFMA tiles).
// ---------------------------------------------------------------------------
__global__ __launch_bounds__(256, 4) void gemm_out(
    const _Float16* __restrict__ A, const _Float16* __restrict__ W,
    const float* __restrict__ bo, float* __restrict__ dout)
{
    __shared__ _Float16 As[64 * 32];
    __shared__ _Float16 Bs[128 * 32];
    const int t = threadIdx.x;
    const int bm = blockIdx.x, bn = blockIdx.y;
    const int wave = t >> 6, lane = t & 63;
    const int wm = (wave >> 1) * 32, wn = (wave & 1) * 64;
    const int quad = lane >> 4, l16 = lane & 15;

    f32x4 acc[2][4];
#pragma unroll
    for (int a = 0; a < 2; a++)
#pragma unroll
        for (int b2 = 0; b2 < 4; b2++) acc[a][b2] = (f32x4){0.f, 0.f, 0.f, 0.f};

    const _Float16* Ab = A + (size_t)bm * 64 * 512;
    const _Float16* Bb = W + (size_t)bn * 128 * 512;
    const int srow = t >> 2, scol = (t & 3) * 8;

    for (int k0 = 0; k0 < 512; k0 += 32) {
        __syncthreads();
        lds_load16(Ab + (size_t)srow * 512 + k0 + scol, As + t * 8);
        lds_load16(Bb + (size_t)srow * 512 + k0 + scol, Bs + t * 8);
        lds_load16(Bb + (size_t)(srow + 64) * 512 + k0 + scol, Bs + 2048 + t * 8);
        __syncthreads();
        half8 af[2], bf[4];
#pragma unroll
        for (int mi = 0; mi < 2; mi++)
            af[mi] = *(const half8*)&As[(wm + mi * 16 + l16) * 32 + quad * 8];
#pragma unroll
        for (int ni = 0; ni < 4; ni++)
            bf[ni] = *(const half8*)&Bs[(wn + ni * 16 + l16) * 32 + quad * 8];
#pragma unroll
        for (int mi = 0; mi < 2; mi++)
#pragma unroll
            for (int ni = 0; ni < 4; ni++)
                acc[mi][ni] = __builtin_amdgcn_mfma_f32_16x16x32_f16(
                    af[mi], bf[ni], acc[mi][ni], 0, 0, 0);
    }
#pragma unroll
    for (int mi = 0; mi < 2; mi++) {
#pragma unroll
        for (int r = 0; r < 4; r++) {
            const int m = bm * 64 + wm + mi * 16 + quad * 4 + r;
#pragma unroll
            for (int ni = 0; ni < 4; ni++) {
                const int n = bn * 128 + wn + ni * 16 + l16;
                dout[(size_t)m * 512 + n] = acc[mi][ni][r] + bo[n];
            }
        }
    }
}

// ---------------------------------------------------------------------------
extern "C" void kernel_launch(void* const* d_in, const int* in_sizes, int n_in,
                              void* d_out, int out_size, void* d_ws, size_t ws_size,
                              hipStream_t stream)
{
    (void)in_sizes; (void)n_in; (void)out_size; (void)ws_size;
    const float* nodes    = (const float*)d_in[0];
    const float* edges    = (const float*)d_in[1];
    const float* Wq       = (const float*)d_in[2];
    const float* bq       = (const float*)d_in[3];
    const float* Wk       = (const float*)d_in[4];
    const float* bk       = (const float*)d_in[5];
    const float* Wv       = (const float*)d_in[6];
    const float* bv       = (const float*)d_in[7];
    const float* rel_bias = (const float*)d_in[8];
    const float* Wo       = (const float*)d_in[9];
    const float* bo       = (const float*)d_in[10];
    float* out = (float*)d_out;

    char* ws = (char*)d_ws;
    _Float16* x16    = (_Float16*)(ws);              //  8,388,608 B
    _Float16* wcat   = (_Float16*)(ws +  8388608);   //  1,572,864 B
    _Float16* wo16   = (_Float16*)(ws +  9961472);   //    524,288 B
    _Float16* q16    = (_Float16*)(ws + 10485760);   //  8,388,608 B
    _Float16* k16    = (_Float16*)(ws + 18874368);   //  8,388,608 B
    _Float16* v16    = (_Float16*)(ws + 27262976);   //  8,388,608 B
    _Float16* attn16 = (_Float16*)(ws + 35651584);   //  8,388,608 B

    hipLaunchKernelGGL(prep_convert, dim3(4096), dim3(256), 0, stream,
                       nodes, Wq, Wk, Wv, Wo, x16, wcat, wo16);
    hipLaunchKernelGGL(gemm_qkv, dim3(64, 12), dim3(256), 0, stream,
                       x16, wcat, bq, bk, bv, q16, k16, v16);
    hipLaunchKernelGGL(attn_fused, dim3(8, 64), dim3(256), 0, stream,
                       q16, k16, v16, edges, rel_bias, attn16);
    hipLaunchKernelGGL(gemm_out, dim3(128, 4), dim3(256), 0, stream,
                       attn16, wo16, bo, out);
}

// Round 5
// 164.107 us; speedup vs baseline: 1.0575x; 1.0129x over previous
//
#include <hip/hip_runtime.h>
#include <hip/hip_bf16.h>
#include <hip/hip_fp16.h>
#include <stdint.h>

typedef _Float16 half8 __attribute__((ext_vector_type(8)));
typedef _Float16 half4_t __attribute__((ext_vector_type(4)));
typedef float f32x4 __attribute__((ext_vector_type(4)));

// async global->LDS, 16B per lane. LDS dst must be wave-uniform base + lane*16.
__device__ __forceinline__ void lds_load16(const _Float16* g, _Float16* l) {
    __builtin_amdgcn_global_load_lds(
        (const __attribute__((address_space(1))) void*)g,
        (__attribute__((address_space(3))) void*)l, 16, 0, 0);
}

// ---------------------------------------------------------------------------
// fp32 -> fp16 conversions: nodes (8192x512), Wcat = [Wq;Wk;Wv], Wo
// ---------------------------------------------------------------------------
__global__ __launch_bounds__(256) void prep_convert(
    const float* __restrict__ nodes, const float* __restrict__ wq,
    const float* __restrict__ wk, const float* __restrict__ wv,
    const float* __restrict__ wo,
    _Float16* __restrict__ x16, _Float16* __restrict__ wcat,
    _Float16* __restrict__ wo16)
{
    const int t = blockIdx.x * 256 + threadIdx.x;   // 0 .. 1048575
    {
        const float4 v = ((const float4*)nodes)[t];
        half4_t o;
        o[0] = (_Float16)v.x; o[1] = (_Float16)v.y;
        o[2] = (_Float16)v.z; o[3] = (_Float16)v.w;
        *(half4_t*)(x16 + (size_t)t * 4) = o;
    }
    if (t < 65536) {
        float4 v; half4_t o;
        v = ((const float4*)wq)[t];
        o[0]=(_Float16)v.x; o[1]=(_Float16)v.y; o[2]=(_Float16)v.z; o[3]=(_Float16)v.w;
        *(half4_t*)(wcat + (size_t)t * 4) = o;
        v = ((const float4*)wk)[t];
        o[0]=(_Float16)v.x; o[1]=(_Float16)v.y; o[2]=(_Float16)v.z; o[3]=(_Float16)v.w;
        *(half4_t*)(wcat + 262144 + (size_t)t * 4) = o;
        v = ((const float4*)wv)[t];
        o[0]=(_Float16)v.x; o[1]=(_Float16)v.y; o[2]=(_Float16)v.z; o[3]=(_Float16)v.w;
        *(half4_t*)(wcat + 524288 + (size_t)t * 4) = o;
        v = ((const float4*)wo)[t];
        o[0]=(_Float16)v.x; o[1]=(_Float16)v.y; o[2]=(_Float16)v.z; o[3]=(_Float16)v.w;
        *(half4_t*)(wo16 + (size_t)t * 4) = o;
    }
}

// ---------------------------------------------------------------------------
// QKV projection: X[8192,512] @ Wcat[1536,512]^T -> scatter q/k/v [bh][i][d]
// q is pre-scaled by 1/sqrt(64) here (free in the epilogue).
// ---------------------------------------------------------------------------
__global__ __launch_bounds__(256, 3) void gemm_qkv(
    const _Float16* __restrict__ X, const _Float16* __restrict__ Wcat,
    const float* __restrict__ bq, const float* __restrict__ bk,
    const float* __restrict__ bv,
    _Float16* __restrict__ q16, _Float16* __restrict__ k16,
    _Float16* __restrict__ v16)
{
    __shared__ _Float16 As[128 * 32];
    __shared__ _Float16 Bs[128 * 32];
    const int t = threadIdx.x;
    const int bm = blockIdx.x, bn = blockIdx.y;
    const int wave = t >> 6, lane = t & 63;
    const int wm = (wave >> 1) * 64, wn = (wave & 1) * 64;
    const int quad = lane >> 4, l16 = lane & 15;

    f32x4 acc[4][4];
#pragma unroll
    for (int a = 0; a < 4; a++)
#pragma unroll
        for (int b2 = 0; b2 < 4; b2++) acc[a][b2] = (f32x4){0.f, 0.f, 0.f, 0.f};

    const _Float16* Ab = X + (size_t)bm * 128 * 512;
    const _Float16* Bb = Wcat + (size_t)bn * 128 * 512;
    const int srow = t >> 2, scol = (t & 3) * 8;

    for (int k0 = 0; k0 < 512; k0 += 32) {
        __syncthreads();
        lds_load16(Ab + (size_t)srow * 512 + k0 + scol, As + t * 8);
        lds_load16(Ab + (size_t)(srow + 64) * 512 + k0 + scol, As + 2048 + t * 8);
        lds_load16(Bb + (size_t)srow * 512 + k0 + scol, Bs + t * 8);
        lds_load16(Bb + (size_t)(srow + 64) * 512 + k0 + scol, Bs + 2048 + t * 8);
        __syncthreads();
        half8 af[4], bf[4];
#pragma unroll
        for (int mi = 0; mi < 4; mi++)
            af[mi] = *(const half8*)&As[(wm + mi * 16 + l16) * 32 + quad * 8];
#pragma unroll
        for (int ni = 0; ni < 4; ni++)
            bf[ni] = *(const half8*)&Bs[(wn + ni * 16 + l16) * 32 + quad * 8];
#pragma unroll
        for (int mi = 0; mi < 4; mi++)
#pragma unroll
            for (int ni = 0; ni < 4; ni++)
                acc[mi][ni] = __builtin_amdgcn_mfma_f32_16x16x32_f16(
                    af[mi], bf[ni], acc[mi][ni], 0, 0, 0);
    }

    const int sel = bn >> 2;
    const float* bias = sel == 0 ? bq : (sel == 1 ? bk : bv);
    _Float16* outp = sel == 0 ? q16 : (sel == 1 ? k16 : v16);
    const float scale = sel == 0 ? 0.125f : 1.0f;   // fold 1/sqrt(D) into q
    const int colbase = (bn & 3) * 128 + wn + l16;
#pragma unroll
    for (int mi = 0; mi < 4; mi++) {
#pragma unroll
        for (int r = 0; r < 4; r++) {
            const int m = bm * 128 + wm + mi * 16 + quad * 4 + r;
            const int ii = m >> 3, bb = m & 7;
#pragma unroll
            for (int ni = 0; ni < 4; ni++) {
                const int f = colbase + ni * 16;
                const int hh = f >> 6, dd = f & 63;
                const float val = (acc[mi][ni][r] + bias[f]) * scale;
                outp[(size_t)((bb * 8 + hh) * 1024 + ii) * 64 + dd] = (_Float16)val;
            }
        }
    }
}

// ---------------------------------------------------------------------------
// Flash-style MFMA attention, register-pipelined.
// Block = (b,h) x 128 q-rows; grid (64,8): x=bh, y=i0-idx, so the 8 blocks
// sharing one bh's K/V land on the same XCD (lin%8 == bh%8) -> K/V L2-resident.
// Pipeline: K/V + edge loads for tile jt+64 issue right after barrier 2 and
// are consumed at the next iteration's LDS-write -> HBM/L2 latency hidden
// behind the full compute section (register loads don't drain at barriers).
// ---------------------------------------------------------------------------
__global__ __launch_bounds__(256, 2) void attn_fused(
    const _Float16* __restrict__ q16, const _Float16* __restrict__ k16,
    const _Float16* __restrict__ v16, const float* __restrict__ edges,
    const float* __restrict__ rel_bias, _Float16* __restrict__ attn16)
{
    __shared__ _Float16 Qs[128][68];    // 17,408 B
    __shared__ _Float16 Ks[64][68];     //  8,704 B
    __shared__ _Float16 Vts[64][70];    //  8,960 B (V^T; write conflicts <=4-way)
    __shared__ _Float16 Ps[128][68];    // 17,408 B (store pattern conflict-free)

    const int t = threadIdx.x;
    const int bh = blockIdx.x;
    const int b = bh >> 3, h = bh & 7;
    const int i0 = blockIdx.y * 128;
    const int wave = t >> 6, lane = t & 63;
    const int quad = lane >> 4, l16 = lane & 15;
    const int qb = wave * 32;
    const float rb = rel_bias[h];
    const float SHIFT = 5.545177444f;   // 8*ln2

    const _Float16* Qb = q16 + (size_t)bh * 1024 * 64;
    const _Float16* Kb = k16 + (size_t)bh * 1024 * 64;
    const _Float16* Vb = v16 + (size_t)bh * 1024 * 64;

    const int srow = t >> 2, scol = (t & 3) * 16;

    {   // Q tile 128x64 (already scaled by 1/8 in gemm_qkv)
#pragma unroll
        for (int rr = 0; rr < 128; rr += 64) {
            *(half8*)&Qs[rr + srow][scol] =
                *(const half8*)(Qb + (size_t)(i0 + rr + srow) * 64 + scol);
            *(half8*)&Qs[rr + srow][scol + 8] =
                *(const half8*)(Qb + (size_t)(i0 + rr + srow) * 64 + scol + 8);
        }
    }

    f32x4 acc_o[2][4];
    float lsum[2][4];
#pragma unroll
    for (int mt = 0; mt < 2; mt++) {
#pragma unroll
        for (int nd = 0; nd < 4; nd++) acc_o[mt][nd] = (f32x4){0.f, 0.f, 0.f, 0.f};
#pragma unroll
        for (int r = 0; r < 4; r++) lsum[mt][r] = 0.f;
    }

    // ---- pipeline prologue: loads for jt=0 ----
    half8 kp0, kp1, vp0, vp1;
    float ebp[2][4][4];
    kp0 = *(const half8*)(Kb + (size_t)srow * 64 + scol);
    kp1 = *(const half8*)(Kb + (size_t)srow * 64 + scol + 8);
    vp0 = *(const half8*)(Vb + (size_t)srow * 64 + scol);
    vp1 = *(const half8*)(Vb + (size_t)srow * 64 + scol + 8);
#pragma unroll
    for (int mt = 0; mt < 2; mt++) {
        const size_t rowb = (size_t)(i0 + qb + mt * 16 + quad * 4) * 1024;
#pragma unroll
        for (int nt = 0; nt < 4; nt++)
#pragma unroll
            for (int r = 0; r < 4; r++)
                ebp[mt][nt][r] = edges[rowb + (size_t)r * 1024 + nt * 16 + l16];
    }

    for (int jt = 0; jt < 1024; jt += 64) {
        __syncthreads();   // previous iteration's LDS reads done
        {   // commit prefetched K / V^T to LDS
            *(half8*)&Ks[srow][scol]     = kp0;
            *(half8*)&Ks[srow][scol + 8] = kp1;
#pragma unroll
            for (int e = 0; e < 8; e++) {
                Vts[scol + e][srow]     = vp0[e];
                Vts[scol + 8 + e][srow] = vp1[e];
            }
        }
        // current-iter edge bias
        float ebc[2][4][4];
#pragma unroll
        for (int mt = 0; mt < 2; mt++)
#pragma unroll
            for (int nt = 0; nt < 4; nt++)
#pragma unroll
                for (int r = 0; r < 4; r++) ebc[mt][nt][r] = ebp[mt][nt][r];
        __syncthreads();

        // ---- issue next-tile loads (consumed next iteration) ----
        const int jn = jt + 64;
        if (jn < 1024) {
            kp0 = *(const half8*)(Kb + (size_t)(jn + srow) * 64 + scol);
            kp1 = *(const half8*)(Kb + (size_t)(jn + srow) * 64 + scol + 8);
            vp0 = *(const half8*)(Vb + (size_t)(jn + srow) * 64 + scol);
            vp1 = *(const half8*)(Vb + (size_t)(jn + srow) * 64 + scol + 8);
#pragma unroll
            for (int mt = 0; mt < 2; mt++) {
                const size_t rowb = (size_t)(i0 + qb + mt * 16 + quad * 4) * 1024;
#pragma unroll
                for (int nt = 0; nt < 4; nt++)
#pragma unroll
                    for (int r = 0; r < 4; r++)
                        ebp[mt][nt][r] = edges[rowb + (size_t)r * 1024 + jn + nt * 16 + l16];
            }
        }

        // ---- S = Q K^T ----
        f32x4 s[2][4];
#pragma unroll
        for (int mt = 0; mt < 2; mt++)
#pragma unroll
            for (int nt = 0; nt < 4; nt++) s[mt][nt] = (f32x4){0.f, 0.f, 0.f, 0.f};
#pragma unroll
        for (int kk = 0; kk < 2; kk++) {
            half8 aq[2], bk8[4];
#pragma unroll
            for (int mt = 0; mt < 2; mt++)
                aq[mt] = *(const half8*)&Qs[qb + mt * 16 + l16][kk * 32 + quad * 8];
#pragma unroll
            for (int nt = 0; nt < 4; nt++)
                bk8[nt] = *(const half8*)&Ks[nt * 16 + l16][kk * 32 + quad * 8];
#pragma unroll
            for (int mt = 0; mt < 2; mt++)
#pragma unroll
                for (int nt = 0; nt < 4; nt++)
                    s[mt][nt] = __builtin_amdgcn_mfma_f32_16x16x32_f16(
                        aq[mt], bk8[nt], s[mt][nt], 0, 0, 0);
        }

        // ---- bias + exp + partial rowsum + f16 P->LDS (wave-private rows) ----
#pragma unroll
        for (int mt = 0; mt < 2; mt++)
#pragma unroll
            for (int nt = 0; nt < 4; nt++)
#pragma unroll
                for (int r = 0; r < 4; r++) {
                    const float sv = fmaf(ebc[mt][nt][r], rb, s[mt][nt][r]);
                    const float p = __expf(sv - SHIFT);
                    lsum[mt][r] += p;
                    Ps[qb + mt * 16 + quad * 4 + r][nt * 16 + l16] = (_Float16)p;
                }

        // ---- P A-frags (direct f16 read) + PV MFMA ----
#pragma unroll
        for (int kk = 0; kk < 2; kk++) {
            half8 pa[2];
#pragma unroll
            for (int mt = 0; mt < 2; mt++)
                pa[mt] = *(const half8*)&Ps[qb + mt * 16 + l16][kk * 32 + quad * 8];
#pragma unroll
            for (int nd = 0; nd < 4; nd++) {
                half8 vb8 = *(const half8*)&Vts[nd * 16 + l16][kk * 32 + quad * 8];
#pragma unroll
                for (int mt = 0; mt < 2; mt++)
                    acc_o[mt][nd] = __builtin_amdgcn_mfma_f32_16x16x32_f16(
                        pa[mt], vb8, acc_o[mt][nd], 0, 0, 0);
            }
        }
    }

    // ---- finalize: reduce lsum over the 16 col-lanes, divide, store ----
#pragma unroll
    for (int mt = 0; mt < 2; mt++)
#pragma unroll
        for (int r = 0; r < 4; r++) {
            float l = lsum[mt][r];
#pragma unroll
            for (int d = 1; d < 16; d <<= 1) l += __shfl_xor(l, d);
            lsum[mt][r] = 1.0f / l;
        }
#pragma unroll
    for (int mt = 0; mt < 2; mt++)
#pragma unroll
        for (int r = 0; r < 4; r++) {
            const int i = i0 + qb + mt * 16 + quad * 4 + r;
            _Float16* orow = attn16 + ((size_t)i * 8 + b) * 512 + h * 64;
#pragma unroll
            for (int nd = 0; nd < 4; nd++)
                orow[nd * 16 + l16] = (_Float16)(acc_o[mt][nd][r] * lsum[mt][r]);
        }
}

// ---------------------------------------------------------------------------
// Output projection: attn16[8192,512] @ Wo[512,512]^T + bo -> d_out fp32
// 64x128 tiles -> grid (128,4) = 512 blocks = 2 blocks/CU.
// ---------------------------------------------------------------------------
__global__ __launch_bounds__(256, 4) void gemm_out(
    const _Float16* __restrict__ A, const _Float16* __restrict__ W,
    const float* __restrict__ bo, float* __restrict__ dout)
{
    __shared__ _Float16 As[64 * 32];
    __shared__ _Float16 Bs[128 * 32];
    const int t = threadIdx.x;
    const int bm = blockIdx.x, bn = blockIdx.y;
    const int wave = t >> 6, lane = t & 63;
    const int wm = (wave >> 1) * 32, wn = (wave & 1) * 64;
    const int quad = lane >> 4, l16 = lane & 15;

    f32x4 acc[2][4];
#pragma unroll
    for (int a = 0; a < 2; a++)
#pragma unroll
        for (int b2 = 0; b2 < 4; b2++) acc[a][b2] = (f32x4){0.f, 0.f, 0.f, 0.f};

    const _Float16* Ab = A + (size_t)bm * 64 * 512;
    const _Float16* Bb = W + (size_t)bn * 128 * 512;
    const int srow = t >> 2, scol = (t & 3) * 8;

    for (int k0 = 0; k0 < 512; k0 += 32) {
        __syncthreads();
        lds_load16(Ab + (size_t)srow * 512 + k0 + scol, As + t * 8);
        lds_load16(Bb + (size_t)srow * 512 + k0 + scol, Bs + t * 8);
        lds_load16(Bb + (size_t)(srow + 64) * 512 + k0 + scol, Bs + 2048 + t * 8);
        __syncthreads();
        half8 af[2], bf[4];
#pragma unroll
        for (int mi = 0; mi < 2; mi++)
            af[mi] = *(const half8*)&As[(wm + mi * 16 + l16) * 32 + quad * 8];
#pragma unroll
        for (int ni = 0; ni < 4; ni++)
            bf[ni] = *(const half8*)&Bs[(wn + ni * 16 + l16) * 32 + quad * 8];
#pragma unroll
        for (int mi = 0; mi < 2; mi++)
#pragma unroll
            for (int ni = 0; ni < 4; ni++)
                acc[mi][ni] = __builtin_amdgcn_mfma_f32_16x16x32_f16(
                    af[mi], bf[ni], acc[mi][ni], 0, 0, 0);
    }
#pragma unroll
    for (int mi = 0; mi < 2; mi++) {
#pragma unroll
        for (int r = 0; r < 4; r++) {
            const int m = bm * 64 + wm + mi * 16 + quad * 4 + r;
#pragma unroll
            for (int ni = 0; ni < 4; ni++) {
                const int n = bn * 128 + wn + ni * 16 + l16;
                dout[(size_t)m * 512 + n] = acc[mi][ni][r] + bo[n];
            }
        }
    }
}

// ---------------------------------------------------------------------------
extern "C" void kernel_launch(void* const* d_in, const int* in_sizes, int n_in,
                              void* d_out, int out_size, void* d_ws, size_t ws_size,
                              hipStream_t stream)
{
    (void)in_sizes; (void)n_in; (void)out_size; (void)ws_size;
    const float* nodes    = (const float*)d_in[0];
    const float* edges    = (const float*)d_in[1];
    const float* Wq       = (const float*)d_in[2];
    const float* bq       = (const float*)d_in[3];
    const float* Wk       = (const float*)d_in[4];
    const float* bk       = (const float*)d_in[5];
    const float* Wv       = (const float*)d_in[6];
    const float* bv       = (const float*)d_in[7];
    const float* rel_bias = (const float*)d_in[8];
    const float* Wo       = (const float*)d_in[9];
    const float* bo       = (const float*)d_in[10];
    float* out = (float*)d_out;

    char* ws = (char*)d_ws;
    _Float16* x16    = (_Float16*)(ws);              //  8,388,608 B
    _Float16* wcat   = (_Float16*)(ws +  8388608);   //  1,572,864 B
    _Float16* wo16   = (_Float16*)(ws +  9961472);   //    524,288 B
    _Float16* q16    = (_Float16*)(ws + 10485760);   //  8,388,608 B
    _Float16* k16    = (_Float16*)(ws + 18874368);   //  8,388,608 B
    _Float16* v16    = (_Float16*)(ws + 27262976);   //  8,388,608 B
    _Float16* attn16 = (_Float16*)(ws + 35651584);   //  8,388,608 B

    hipLaunchKernelGGL(prep_convert, dim3(4096), dim3(256), 0, stream,
                       nodes, Wq, Wk, Wv, Wo, x16, wcat, wo16);
    hipLaunchKernelGGL(gemm_qkv, dim3(64, 12), dim3(256), 0, stream,
                       x16, wcat, bq, bk, bv, q16, k16, v16);
    hipLaunchKernelGGL(attn_fused, dim3(64, 8), dim3(256), 0, stream,
                       q16, k16, v16, edges, rel_bias, attn16);
    hipLaunchKernelGGL(gemm_out, dim3(128, 4), dim3(256), 0, stream,
                       attn16, wo16, bo, out);
}